// Round 1
// baseline (835.059 us; speedup 1.0000x reference)
//
#include <hip/hip_runtime.h>
#include <math.h>

#define DMODEL 1024
#define DSTATE 16
#define DCONV 4
#define DINNER 2048
#define BATCH 2
#define SEQ 1024
#define BT (BATCH*SEQ)   // 2048

// ---------------------------------------------------------------------------
// Generic fp32 SGEMM: C[M,N] = A[M,K] @ B[K,N], all row-major, exact tiles.
// ---------------------------------------------------------------------------
template<int BM, int BN, int BK, int TM, int TN>
__global__ __launch_bounds__(256) void sgemm(const float* __restrict__ A,
                                             const float* __restrict__ B,
                                             float* __restrict__ C,
                                             int M, int N, int K)
{
    __shared__ float As[BK][BM];
    __shared__ float Bs[BK][BN];
    constexpr int NT  = 256;
    constexpr int AF4 = (BM * BK) / (NT * 4);   // float4 loads per thread (A)
    constexpr int BF4 = (BN * BK) / (NT * 4);   // float4 loads per thread (B)
    constexpr int TXN = BN / TN;                 // threads along n

    const int tid = threadIdx.x;
    const int bn  = blockIdx.x * BN;
    const int bm  = blockIdx.y * BM;
    const int tx  = tid % TXN;
    const int ty  = tid / TXN;

    float acc[TM][TN] = {};

    for (int k0 = 0; k0 < K; k0 += BK) {
        // --- stage A tile (transposed into LDS) ---
#pragma unroll
        for (int j = 0; j < AF4; j++) {
            int e4  = (j * NT + tid) * 4;
            int row = e4 / BK;
            int kk  = e4 % BK;
            float4 v = *(const float4*)&A[(size_t)(bm + row) * K + k0 + kk];
            As[kk + 0][row] = v.x;
            As[kk + 1][row] = v.y;
            As[kk + 2][row] = v.z;
            As[kk + 3][row] = v.w;
        }
        // --- stage B tile ---
#pragma unroll
        for (int j = 0; j < BF4; j++) {
            int e4 = (j * NT + tid) * 4;
            int r  = e4 / BN;
            int c  = e4 % BN;
            *(float4*)&Bs[r][c] = *(const float4*)&B[(size_t)(k0 + r) * N + bn + c];
        }
        __syncthreads();

#pragma unroll
        for (int k = 0; k < BK; k++) {
            float af[TM], bf[TN];
#pragma unroll
            for (int i = 0; i < TM; i++) af[i] = As[k][ty * TM + i];
#pragma unroll
            for (int j = 0; j < TN; j++) bf[j] = Bs[k][tx * TN + j];
#pragma unroll
            for (int i = 0; i < TM; i++)
#pragma unroll
                for (int j = 0; j < TN; j++)
                    acc[i][j] = fmaf(af[i], bf[j], acc[i][j]);
        }
        __syncthreads();
    }

#pragma unroll
    for (int i = 0; i < TM; i++) {
        size_t cro = (size_t)(bm + ty * TM + i) * N + bn + tx * TN;
#pragma unroll
        for (int j4 = 0; j4 < TN / 4; j4++) {
            float4 v = make_float4(acc[i][j4*4+0], acc[i][j4*4+1],
                                   acc[i][j4*4+2], acc[i][j4*4+3]);
            *(float4*)&C[cro + j4 * 4] = v;
        }
    }
}

// ---------------------------------------------------------------------------
// Depthwise causal conv(4) + bias + SiLU on the x-half of xz.
// Writes x_branch row-major (B,T,DINNER) AND transposed xT (B,DINNER,T).
// Block handles (b, 64 d, 64 t). Grid: (T/64, DINNER/64, B)
// ---------------------------------------------------------------------------
__global__ __launch_bounds__(256) void conv_silu_kernel(const float* __restrict__ xz,
                                                        const float* __restrict__ cw,
                                                        const float* __restrict__ cb,
                                                        float* __restrict__ xb_rm,
                                                        float* __restrict__ xT)
{
    __shared__ float tile[64 + 3][64];  // rows: t0-3 .. t0+63
    __shared__ float outT[64][65];      // [t][d], pad 65 to kill bank conflicts

    const int b  = blockIdx.z;
    const int t0 = blockIdx.x * 64;
    const int d0 = blockIdx.y * 64;
    const int tid = threadIdx.x;

    // load 67 x 64 input tile (float4 along d)
    for (int e = tid; e < 67 * 16; e += 256) {
        int r  = e / 16;
        int c4 = e % 16;
        int t  = t0 - 3 + r;
        float4 v = make_float4(0.f, 0.f, 0.f, 0.f);
        if (t >= 0)
            v = *(const float4*)&xz[((size_t)b * SEQ + t) * (2 * DINNER) + d0 + c4 * 4];
        *(float4*)&tile[r][c4 * 4] = v;
    }
    __syncthreads();

    const int dl = tid & 63;          // local d
    const int tb = tid >> 6;          // 0..3
    const int d  = d0 + dl;
    const float w0 = cw[d * 4 + 0];
    const float w1 = cw[d * 4 + 1];
    const float w2 = cw[d * 4 + 2];
    const float w3 = cw[d * 4 + 3];
    const float bias = cb[d];

#pragma unroll
    for (int ii = 0; ii < 16; ii++) {
        int tl = tb + 4 * ii;         // local t, 0..63
        float s = bias;
        s = fmaf(tile[tl + 0][dl], w0, s);
        s = fmaf(tile[tl + 1][dl], w1, s);
        s = fmaf(tile[tl + 2][dl], w2, s);
        s = fmaf(tile[tl + 3][dl], w3, s);
        // SiLU
        float sil = s / (1.f + __expf(-s));
        xb_rm[((size_t)b * SEQ + t0 + tl) * DINNER + d] = sil;
        outT[tl][dl] = sil;
    }
    __syncthreads();

    // transposed write: coalesced along t
#pragma unroll
    for (int ii = 0; ii < 16; ii++) {
        int dl2 = (tid >> 6) + 4 * ii;   // 0..63
        int tl2 = tid & 63;
        xT[((size_t)b * DINNER + d0 + dl2) * SEQ + t0 + tl2] = outT[tl2][dl2];
    }
}

// ---------------------------------------------------------------------------
// x_ssm = x_branch @ x_proj_w  -> split into B_t (B,T,16), C_t (B,T,16), dtraw (B,T)
// thread per (bt, n): 2048*33 = 67584 threads = 264 blocks exact.
// ---------------------------------------------------------------------------
__global__ __launch_bounds__(256) void xproj_kernel(const float* __restrict__ xb,
                                                    const float* __restrict__ w,
                                                    float* __restrict__ Btb,
                                                    float* __restrict__ Ctb,
                                                    float* __restrict__ dtraw)
{
    int idx = blockIdx.x * 256 + threadIdx.x;
    int bt = idx / 33;
    int n  = idx % 33;
    const float* xrow = xb + (size_t)bt * DINNER;
    float acc = 0.f;
#pragma unroll 8
    for (int k = 0; k < DINNER; k++)
        acc = fmaf(xrow[k], w[(size_t)k * 33 + n], acc);
    if (n < 16)       Btb[bt * 16 + n]      = acc;
    else if (n < 32)  Ctb[bt * 16 + n - 16] = acc;
    else              dtraw[bt]             = acc;
}

__device__ __forceinline__ float softplusf(float x) {
    return (x > 20.f) ? x : log1pf(__expf(x));
}

// ---------------------------------------------------------------------------
// dtT[b][d][t] = softplus(dtraw[b][t]*dtw[d] + dtb[d]); transposed layout.
// grid: B*DINNER blocks, 256 threads, 4 t per thread.
// ---------------------------------------------------------------------------
__global__ __launch_bounds__(256) void dt_kernel(const float* __restrict__ dtraw,
                                                 const float* __restrict__ dtw,
                                                 const float* __restrict__ dtb,
                                                 float* __restrict__ dtT)
{
    int bd = blockIdx.x;
    int b  = bd / DINNER;
    int d  = bd % DINNER;
    float w  = dtw[d];
    float bi = dtb[d];
    int t = threadIdx.x * 4;
    float4 r = *(const float4*)&dtraw[b * SEQ + t];
    float4 o;
    o.x = softplusf(fmaf(r.x, w, bi));
    o.y = softplusf(fmaf(r.y, w, bi));
    o.z = softplusf(fmaf(r.z, w, bi));
    o.w = softplusf(fmaf(r.w, w, bi));
    *(float4*)&dtT[(size_t)bd * SEQ + t] = o;
}

// ---------------------------------------------------------------------------
// Selective scan. lane-per-(d,s): 16 lanes per channel, 16 channels per block.
// grid: B * DINNER/16 = 256 blocks, 256 threads.
// ---------------------------------------------------------------------------
__global__ __launch_bounds__(256) void scan_kernel(const float* __restrict__ dtT,
                                                   const float* __restrict__ xT,
                                                   const float* __restrict__ Btb,
                                                   const float* __restrict__ Ctb,
                                                   const float* __restrict__ A_log,
                                                   float* __restrict__ y)
{
    const int tid = threadIdx.x;
    const int g   = tid >> 4;        // channel group in block, 0..15
    const int s   = tid & 15;        // state index
    const int blk = blockIdx.x;      // 0..255
    const int b   = blk >> 7;
    const int d   = (blk & 127) * 16 + g;

    const float As = -expf(A_log[d * DSTATE + s]);
    const float* dtp = dtT + ((size_t)b * DINNER + d) * SEQ;
    const float* xp  = xT  + ((size_t)b * DINNER + d) * SEQ;
    const float* Bp  = Btb + (size_t)b * SEQ * 16 + s;
    const float* Cp  = Ctb + (size_t)b * SEQ * 16 + s;
    float* yp = y + (size_t)b * SEQ * DINNER + d;

    float h = 0.f;
    for (int tc = 0; tc < SEQ; tc += 16) {
        float dtv = dtp[tc + s];   // coalesced 16-chunk
        float xv  = xp[tc + s];
#pragma unroll
        for (int i = 0; i < 16; i++) {
            float dti = __shfl(dtv, i, 16);
            float xi  = __shfl(xv,  i, 16);
            int t = tc + i;
            float bte = Bp[(size_t)t * 16];
            float cte = Cp[(size_t)t * 16];
            float a = __expf(dti * As);
            h = fmaf(a, h, dti * bte * xi);
            float p = h * cte;
            p += __shfl_xor(p, 1, 16);
            p += __shfl_xor(p, 2, 16);
            p += __shfl_xor(p, 4, 16);
            p += __shfl_xor(p, 8, 16);
            if (s == 0) yp[(size_t)t * DINNER] = p;
        }
    }
}

// ---------------------------------------------------------------------------
// y_final = (y_ssm + D*x_branch) * silu(z); in-place on y. float4 elementwise.
// grid: BT*DINNER/4/256 = 4096 blocks
// ---------------------------------------------------------------------------
__global__ __launch_bounds__(256) void fuse_kernel(float* __restrict__ y,
                                                   const float* __restrict__ xb,
                                                   const float* __restrict__ xz,
                                                   const float* __restrict__ Dp)
{
    size_t e  = ((size_t)blockIdx.x * 256 + threadIdx.x) * 4;
    size_t bt = e >> 11;           // / 2048
    int    d  = (int)(e & 2047);
    float4 yv = *(const float4*)&y[e];
    float4 xv = *(const float4*)&xb[e];
    float4 zv = *(const float4*)&xz[bt * (2 * DINNER) + DINNER + d];
    float4 dv = *(const float4*)&Dp[d];
    float4 o;
    o.x = fmaf(dv.x, xv.x, yv.x) * (zv.x / (1.f + __expf(-zv.x)));
    o.y = fmaf(dv.y, xv.y, yv.y) * (zv.y / (1.f + __expf(-zv.y)));
    o.z = fmaf(dv.z, xv.z, yv.z) * (zv.z / (1.f + __expf(-zv.z)));
    o.w = fmaf(dv.w, xv.w, yv.w) * (zv.w / (1.f + __expf(-zv.w)));
    *(float4*)&y[e] = o;
}

// ---------------------------------------------------------------------------
extern "C" void kernel_launch(void* const* d_in, const int* in_sizes, int n_in,
                              void* d_out, int out_size, void* d_ws, size_t ws_size,
                              hipStream_t stream)
{
    const float* x         = (const float*)d_in[0];
    const float* in_proj_w = (const float*)d_in[1];
    const float* conv_w    = (const float*)d_in[2];
    const float* conv_b    = (const float*)d_in[3];
    const float* x_proj_w  = (const float*)d_in[4];
    const float* dt_proj_w = (const float*)d_in[5];
    const float* dt_proj_b = (const float*)d_in[6];
    const float* A_log     = (const float*)d_in[7];
    const float* D_param   = (const float*)d_in[8];
    const float* c_proj_w  = (const float*)d_in[9];
    float* out = (float*)d_out;

    float* ws    = (float*)d_ws;
    float* xz    = ws;                                   // BT*4096
    float* xb    = xz  + (size_t)BT * 4096;              // BT*2048
    float* xT    = xb  + (size_t)BT * DINNER;            // BT*2048
    float* dtT   = xT  + (size_t)BT * DINNER;            // BT*2048
    float* yb    = dtT + (size_t)BT * DINNER;            // BT*2048
    float* Btb   = yb  + (size_t)BT * DINNER;            // BT*16
    float* Ctb   = Btb + (size_t)BT * 16;                // BT*16
    float* dtraw = Ctb + (size_t)BT * 16;                // BT

    // 1. xz = x @ in_proj_w   (2048 x 4096 x 1024)
    sgemm<128, 128, 16, 8, 8><<<dim3(4096 / 128, 2048 / 128), 256, 0, stream>>>(
        x, in_proj_w, xz, BT, 2 * DINNER, DMODEL);

    // 2. conv + bias + silu -> x_branch (row-major + transposed)
    conv_silu_kernel<<<dim3(SEQ / 64, DINNER / 64, BATCH), 256, 0, stream>>>(
        xz, conv_w, conv_b, xb, xT);

    // 3. x_ssm projection -> B_t, C_t, dtraw
    xproj_kernel<<<dim3((BT * 33) / 256), 256, 0, stream>>>(
        xb, x_proj_w, Btb, Ctb, dtraw);

    // 4. dt = softplus(dtraw*w + b), transposed (B,D,T)
    dt_kernel<<<dim3(BATCH * DINNER), 256, 0, stream>>>(
        dtraw, dt_proj_w, dt_proj_b, dtT);

    // 5. selective scan -> y_ssm (B,T,D)
    scan_kernel<<<dim3(BATCH * DINNER / 16), 256, 0, stream>>>(
        dtT, xT, Btb, Ctb, A_log, yb);

    // 6. gate fuse: y = (y + D*xb) * silu(z)
    fuse_kernel<<<dim3((BT * DINNER) / (4 * 256)), 256, 0, stream>>>(
        yb, xb, xz, D_param);

    // 7. out = y @ c_proj_w  (2048 x 1024 x 2048)
    sgemm<64, 128, 16, 4, 8><<<dim3(1024 / 128, 2048 / 64), 256, 0, stream>>>(
        yb, c_proj_w, out, BT, DMODEL, DINNER);
}

// Round 2
// 300.077 us; speedup vs baseline: 2.7828x; 2.7828x over previous
//
#include <hip/hip_runtime.h>
#include <math.h>

#define DMODEL 1024
#define DSTATE 16
#define DCONV 4
#define DINNER 2048
#define BATCH 2
#define SEQ 1024
#define BT (BATCH*SEQ)   // 2048

typedef unsigned short ushort_t;
typedef __attribute__((ext_vector_type(8))) short short8;
typedef __attribute__((ext_vector_type(4))) float f32x4;

__device__ __forceinline__ ushort_t f2bf(float f) {
    union { float f; unsigned int u; } v; v.f = f;
    unsigned int r = v.u + 0x7fffu + ((v.u >> 16) & 1u);
    return (ushort_t)(r >> 16);
}

__device__ __forceinline__ float softplusf(float x) {
    return (x > 20.f) ? x : log1pf(__expf(x));
}

#define GLOAD_LDS16(G, L) \
  __builtin_amdgcn_global_load_lds((const __attribute__((address_space(1))) void*)(G), \
                                   (__attribute__((address_space(3))) void*)(L), 16, 0, 0)

// ---------------------------------------------------------------------------
// cast fp32 -> bf16, same layout. 8 elems / thread.
// ---------------------------------------------------------------------------
__global__ __launch_bounds__(256) void cast_bf16_kernel(const float* __restrict__ in,
                                                        ushort_t* __restrict__ out)
{
    size_t i = ((size_t)blockIdx.x * 256 + threadIdx.x) * 8;
    float4 a = *(const float4*)&in[i];
    float4 b = *(const float4*)&in[i + 4];
    uint4 p;
    p.x = (unsigned)f2bf(a.x) | ((unsigned)f2bf(a.y) << 16);
    p.y = (unsigned)f2bf(a.z) | ((unsigned)f2bf(a.w) << 16);
    p.z = (unsigned)f2bf(b.x) | ((unsigned)f2bf(b.y) << 16);
    p.w = (unsigned)f2bf(b.z) | ((unsigned)f2bf(b.w) << 16);
    *(uint4*)&out[i] = p;
}

// ---------------------------------------------------------------------------
// transpose + cast: in [R][Cc] fp32 -> out [Cc][R] bf16.  grid (Cc/32, R/32).
// ---------------------------------------------------------------------------
__global__ __launch_bounds__(256) void transpose_cast_kernel(const float* __restrict__ in,
                                                             ushort_t* __restrict__ out,
                                                             int R, int Cc)
{
    __shared__ float t[32][33];
    const int r0 = blockIdx.y * 32;
    const int c0 = blockIdx.x * 32;
    const int tid = threadIdx.x;
    {
        int lr = tid >> 3, lc4 = (tid & 7) * 4;
        float4 v = *(const float4*)&in[(size_t)(r0 + lr) * Cc + c0 + lc4];
        t[lr][lc4 + 0] = v.x; t[lr][lc4 + 1] = v.y;
        t[lr][lc4 + 2] = v.z; t[lr][lc4 + 3] = v.w;
    }
    __syncthreads();
    {
        int oc = tid >> 3, rq = (tid & 7) * 4;
        ushort4 u;
        u.x = f2bf(t[rq + 0][oc]);
        u.y = f2bf(t[rq + 1][oc]);
        u.z = f2bf(t[rq + 2][oc]);
        u.w = f2bf(t[rq + 3][oc]);
        *(ushort4*)&out[(size_t)(c0 + oc) * R + r0 + rq] = u;
    }
}

// ---------------------------------------------------------------------------
// bf16 MFMA GEMM: C[M][N] (fp32) = A[M][K] @ Bt[N][K]^T, both bf16 row-major-K.
// m97 structure: BK=32, 4 waves in 2x2, global_load_lds width 16.
// ---------------------------------------------------------------------------
template<int BM, int BN>
__global__ __launch_bounds__(256) void gemm_bt(const ushort_t* __restrict__ A,
                                               const ushort_t* __restrict__ Bt,
                                               float* __restrict__ C,
                                               int M, int N, int K)
{
    constexpr int BK = 32;
    constexpr int AL = BM * BK / (256 * 8);
    constexpr int BL = BN * BK / (256 * 8);
    constexpr int FM = BM / 32;
    constexpr int FN = BN / 32;
    __shared__ __align__(16) ushort_t Al[BM * BK];
    __shared__ __align__(16) ushort_t Bl[BN * BK];

    const int tid  = threadIdx.x;
    const int lane = tid & 63;
    const int wid  = tid >> 6;
    const int wr   = wid >> 1;
    const int wc   = wid & 1;
    const int bm   = blockIdx.y * BM;
    const int bn   = blockIdx.x * BN;

    f32x4 acc[FM][FN] = {};

    for (int k0 = 0; k0 < K; k0 += BK) {
#pragma unroll
        for (int j = 0; j < AL; j++) {
            int chunk = j * 256 + tid;
            int row = chunk >> 2;           // 4 chunks of 8 bf16 per 32-wide row
            int col = (chunk & 3) * 8;
            GLOAD_LDS16(&A[(size_t)(bm + row) * K + k0 + col],
                        &Al[(size_t)(j * 256 + wid * 64) * 8]);
        }
#pragma unroll
        for (int j = 0; j < BL; j++) {
            int chunk = j * 256 + tid;
            int row = chunk >> 2;
            int col = (chunk & 3) * 8;
            GLOAD_LDS16(&Bt[(size_t)(bn + row) * K + k0 + col],
                        &Bl[(size_t)(j * 256 + wid * 64) * 8]);
        }
        __syncthreads();

        short8 af[FM], bf[FN];
#pragma unroll
        for (int m = 0; m < FM; m++)
            af[m] = *(const short8*)&Al[(wr * (BM / 2) + m * 16 + (lane & 15)) * BK + (lane >> 4) * 8];
#pragma unroll
        for (int n = 0; n < FN; n++)
            bf[n] = *(const short8*)&Bl[(wc * (BN / 2) + n * 16 + (lane & 15)) * BK + (lane >> 4) * 8];
#pragma unroll
        for (int m = 0; m < FM; m++)
#pragma unroll
            for (int n = 0; n < FN; n++)
                acc[m][n] = __builtin_amdgcn_mfma_f32_16x16x32_bf16(af[m], bf[n], acc[m][n], 0, 0, 0);
        __syncthreads();
    }

#pragma unroll
    for (int m = 0; m < FM; m++)
#pragma unroll
        for (int n = 0; n < FN; n++) {
            int row0 = bm + wr * (BM / 2) + m * 16 + (lane >> 4) * 4;
            int col  = bn + wc * (BN / 2) + n * 16 + (lane & 15);
#pragma unroll
            for (int r = 0; r < 4; r++)
                C[(size_t)(row0 + r) * N + col] = acc[m][n][r];
        }
}

// ---------------------------------------------------------------------------
// Depthwise causal conv(4) + bias + SiLU, row-major out only.
// ---------------------------------------------------------------------------
__global__ __launch_bounds__(256) void conv_silu_kernel(const float* __restrict__ xz,
                                                        const float* __restrict__ cw,
                                                        const float* __restrict__ cb,
                                                        float* __restrict__ xb_rm)
{
    __shared__ float tile[64 + 3][64];
    const int b  = blockIdx.z;
    const int t0 = blockIdx.x * 64;
    const int d0 = blockIdx.y * 64;
    const int tid = threadIdx.x;

    for (int e = tid; e < 67 * 16; e += 256) {
        int r  = e / 16;
        int c4 = (e % 16) * 4;
        int t  = t0 - 3 + r;
        float4 v = make_float4(0.f, 0.f, 0.f, 0.f);
        if (t >= 0)
            v = *(const float4*)&xz[((size_t)b * SEQ + t) * (2 * DINNER) + d0 + c4];
        *(float4*)&tile[r][c4] = v;
    }
    __syncthreads();

    const int dl = tid & 63;
    const int tb = tid >> 6;
    const int d  = d0 + dl;
    const float w0 = cw[d * 4 + 0], w1 = cw[d * 4 + 1];
    const float w2 = cw[d * 4 + 2], w3 = cw[d * 4 + 3];
    const float bias = cb[d];

#pragma unroll
    for (int ii = 0; ii < 16; ii++) {
        int tl = tb + 4 * ii;
        float s = bias;
        s = fmaf(tile[tl + 0][dl], w0, s);
        s = fmaf(tile[tl + 1][dl], w1, s);
        s = fmaf(tile[tl + 2][dl], w2, s);
        s = fmaf(tile[tl + 3][dl], w3, s);
        float sil = s / (1.f + __expf(-s));
        xb_rm[((size_t)b * SEQ + t0 + tl) * DINNER + d] = sil;
    }
}

// ---------------------------------------------------------------------------
// xproj: B_t/C_t only (cols 0..31). Block: 8 bt rows, thread=(r=tid>>5, n=tid&31).
// ---------------------------------------------------------------------------
__global__ __launch_bounds__(256) void xproj_kernel(const float* __restrict__ xb,
                                                    const float* __restrict__ w,
                                                    float* __restrict__ Btb,
                                                    float* __restrict__ Ctb)
{
    __shared__ float xs[8][256];
    const int bt0 = blockIdx.x * 8;
    const int tid = threadIdx.x;
    const int r = tid >> 5, n = tid & 31;
    float acc = 0.f;
    for (int kc = 0; kc < DINNER; kc += 256) {
#pragma unroll
        for (int j = 0; j < 2; j++) {
            int e4 = (j * 256 + tid) * 4;
            int rr = e4 >> 8, cc = e4 & 255;
            *(float4*)&xs[rr][cc] = *(const float4*)&xb[(size_t)(bt0 + rr) * DINNER + kc + cc];
        }
        __syncthreads();
#pragma unroll 8
        for (int kk = 0; kk < 256; kk++)
            acc = fmaf(xs[r][kk], w[(size_t)(kc + kk) * 33 + n], acc);
        __syncthreads();
    }
    if (n < 16) Btb[(bt0 + r) * 16 + n]      = acc;
    else        Ctb[(bt0 + r) * 16 + n - 16] = acc;
}

// ---------------------------------------------------------------------------
// dtraw[bt] = xb[bt,:] . w[:,32]. One wave per row, 4 rows / block.
// ---------------------------------------------------------------------------
__global__ __launch_bounds__(256) void dtraw_kernel(const float* __restrict__ xb,
                                                    const float* __restrict__ w,
                                                    float* __restrict__ dtraw)
{
    const int bt   = blockIdx.x * 4 + (threadIdx.x >> 6);
    const int lane = threadIdx.x & 63;
    const float* xr = xb + (size_t)bt * DINNER;
    float acc = 0.f;
#pragma unroll 4
    for (int k = lane; k < DINNER; k += 64)
        acc = fmaf(xr[k], w[(size_t)k * 33 + 32], acc);
#pragma unroll
    for (int off = 32; off; off >>= 1) acc += __shfl_xor(acc, off, 64);
    if (lane == 0) dtraw[bt] = acc;
}

// ---------------------------------------------------------------------------
// Chunked selective scan. Lane owns one d-channel (16 states in regs).
// 16 chunks of 64 steps. Block: 256 thr = 16 chunks x 16 d. Grid: B*D/16=256.
// Phase1: per-chunk (prod a, h_end) with h0=0. Phase2: LDS carry propagate.
// Phase3: recompute with true h_start, emit y.
// ---------------------------------------------------------------------------
__global__ __launch_bounds__(256) void scan_kernel(const float* __restrict__ xb,
                                                   const float* __restrict__ dtraw,
                                                   const float* __restrict__ Btb,
                                                   const float* __restrict__ Ctb,
                                                   const float* __restrict__ A_log,
                                                   const float* __restrict__ dtw,
                                                   const float* __restrict__ dtb,
                                                   float* __restrict__ y)
{
    __shared__ float Pl[16][16][17];
    __shared__ float Hl[16][16][17];
    const int tid = threadIdx.x;
    const int dl  = tid & 15;
    const int c   = tid >> 4;
    const int b   = blockIdx.x >> 7;
    const int d   = ((blockIdx.x & 127) << 4) + dl;

    const float wdt = dtw[d];
    const float bdt = dtb[d];
    float As2[16];
#pragma unroll
    for (int s = 0; s < 16; s++)
        As2[s] = -__expf(A_log[d * 16 + s]) * 1.44269504f;

    const float* __restrict__ dtp = dtraw + b * SEQ;
    const float* __restrict__ xp  = xb + (size_t)b * SEQ * DINNER + d;
    const float* __restrict__ Bp  = Btb + (size_t)b * SEQ * 16;
    const float* __restrict__ Cp  = Ctb + (size_t)b * SEQ * 16;
    const int t0 = c * 64;

    float h[16], P[16];
#pragma unroll
    for (int s = 0; s < 16; s++) { h[s] = 0.f; P[s] = 1.f; }

#pragma unroll 2
    for (int i = 0; i < 64; i++) {
        const int t = t0 + i;
        float dt = softplusf(fmaf(dtp[t], wdt, bdt));
        float xv = xp[(size_t)t * DINNER];
        float Bv[16];
        *(float4*)&Bv[0]  = *(const float4*)&Bp[t * 16 + 0];
        *(float4*)&Bv[4]  = *(const float4*)&Bp[t * 16 + 4];
        *(float4*)&Bv[8]  = *(const float4*)&Bp[t * 16 + 8];
        *(float4*)&Bv[12] = *(const float4*)&Bp[t * 16 + 12];
        float dtx = dt * xv;
#pragma unroll
        for (int s = 0; s < 16; s++) {
            float a = exp2f(dt * As2[s]);
            P[s] *= a;
            h[s] = fmaf(a, h[s], Bv[s] * dtx);
        }
    }
#pragma unroll
    for (int s = 0; s < 16; s++) { Pl[c][dl][s] = P[s]; Hl[c][dl][s] = h[s]; }
    __syncthreads();
    {   // carry propagate: thread (dl2, s2) walks 16 chunks
        const int dl2 = tid >> 4, s2 = tid & 15;
        float hs = 0.f;
        for (int cc = 0; cc < 16; cc++) {
            float Pv = Pl[cc][dl2][s2];
            float hv = Hl[cc][dl2][s2];
            Hl[cc][dl2][s2] = hs;          // h_start for chunk cc
            hs = fmaf(Pv, hs, hv);
        }
    }
    __syncthreads();
#pragma unroll
    for (int s = 0; s < 16; s++) h[s] = Hl[c][dl][s];

    float* __restrict__ yp = y + (size_t)b * SEQ * DINNER + d;
#pragma unroll 2
    for (int i = 0; i < 64; i++) {
        const int t = t0 + i;
        float dt = softplusf(fmaf(dtp[t], wdt, bdt));
        float xv = xp[(size_t)t * DINNER];
        float Bv[16], Cv[16];
        *(float4*)&Bv[0]  = *(const float4*)&Bp[t * 16 + 0];
        *(float4*)&Bv[4]  = *(const float4*)&Bp[t * 16 + 4];
        *(float4*)&Bv[8]  = *(const float4*)&Bp[t * 16 + 8];
        *(float4*)&Bv[12] = *(const float4*)&Bp[t * 16 + 12];
        *(float4*)&Cv[0]  = *(const float4*)&Cp[t * 16 + 0];
        *(float4*)&Cv[4]  = *(const float4*)&Cp[t * 16 + 4];
        *(float4*)&Cv[8]  = *(const float4*)&Cp[t * 16 + 8];
        *(float4*)&Cv[12] = *(const float4*)&Cp[t * 16 + 12];
        float dtx = dt * xv;
        float acc = 0.f;
#pragma unroll
        for (int s = 0; s < 16; s++) {
            float a = exp2f(dt * As2[s]);
            h[s] = fmaf(a, h[s], Bv[s] * dtx);
            acc = fmaf(h[s], Cv[s], acc);
        }
        yp[(size_t)t * DINNER] = acc;
    }
}

// ---------------------------------------------------------------------------
// y_final = (y_ssm + D*xb) * silu(z) -> bf16 for the out-proj GEMM.
// ---------------------------------------------------------------------------
__global__ __launch_bounds__(256) void fuse_kernel(const float* __restrict__ y,
                                                   const float* __restrict__ xb,
                                                   const float* __restrict__ xz,
                                                   const float* __restrict__ Dp,
                                                   ushort_t* __restrict__ out)
{
    size_t e  = ((size_t)blockIdx.x * 256 + threadIdx.x) * 4;
    size_t bt = e >> 11;
    int    d  = (int)(e & 2047);
    float4 yv = *(const float4*)&y[e];
    float4 xv = *(const float4*)&xb[e];
    float4 zv = *(const float4*)&xz[bt * (2 * DINNER) + DINNER + d];
    float4 dv = *(const float4*)&Dp[d];
    ushort4 u;
    u.x = f2bf(fmaf(dv.x, xv.x, yv.x) * (zv.x / (1.f + __expf(-zv.x))));
    u.y = f2bf(fmaf(dv.y, xv.y, yv.y) * (zv.y / (1.f + __expf(-zv.y))));
    u.z = f2bf(fmaf(dv.z, xv.z, yv.z) * (zv.z / (1.f + __expf(-zv.z))));
    u.w = f2bf(fmaf(dv.w, xv.w, yv.w) * (zv.w / (1.f + __expf(-zv.w))));
    *(ushort4*)&out[e] = u;
}

// ---------------------------------------------------------------------------
extern "C" void kernel_launch(void* const* d_in, const int* in_sizes, int n_in,
                              void* d_out, int out_size, void* d_ws, size_t ws_size,
                              hipStream_t stream)
{
    const float* x         = (const float*)d_in[0];
    const float* in_proj_w = (const float*)d_in[1];
    const float* conv_w    = (const float*)d_in[2];
    const float* conv_b    = (const float*)d_in[3];
    const float* x_proj_w  = (const float*)d_in[4];
    const float* dt_proj_w = (const float*)d_in[5];
    const float* dt_proj_b = (const float*)d_in[6];
    const float* A_log     = (const float*)d_in[7];
    const float* D_param   = (const float*)d_in[8];
    const float* c_proj_w  = (const float*)d_in[9];
    float* out = (float*)d_out;

    float* ws    = (float*)d_ws;
    float* xz    = ws;                                   // BT*4096 f32
    float* xb    = xz  + (size_t)BT * 4096;              // BT*2048 f32
    float* yb    = xb  + (size_t)BT * DINNER;            // BT*2048 f32
    float* Btb   = yb  + (size_t)BT * DINNER;            // BT*16
    float* Ctb   = Btb + (size_t)BT * 16;                // BT*16
    float* dtraw = Ctb + (size_t)BT * 16;                // BT
    ushort_t* xbf = (ushort_t*)(dtraw + BT);             // BT*1024 bf16
    ushort_t* w1T = xbf + (size_t)BT * DMODEL;           // 4096*1024 bf16
    ushort_t* w2T = w1T + (size_t)(2 * DINNER) * DMODEL; // 1024*2048 bf16
    ushort_t* ygb = w2T + (size_t)DMODEL * DINNER;       // BT*2048 bf16

    // casts
    cast_bf16_kernel<<<dim3((BT * DMODEL) / (8 * 256)), 256, 0, stream>>>(x, xbf);
    transpose_cast_kernel<<<dim3((2 * DINNER) / 32, DMODEL / 32), 256, 0, stream>>>(
        in_proj_w, w1T, DMODEL, 2 * DINNER);
    transpose_cast_kernel<<<dim3(DMODEL / 32, DINNER / 32), 256, 0, stream>>>(
        c_proj_w, w2T, DINNER, DMODEL);

    // 1. xz = x @ in_proj_w (bf16 MFMA)
    gemm_bt<128, 128><<<dim3((2 * DINNER) / 128, BT / 128), 256, 0, stream>>>(
        xbf, w1T, xz, BT, 2 * DINNER, DMODEL);

    // 2. conv + bias + silu
    conv_silu_kernel<<<dim3(SEQ / 64, DINNER / 64, BATCH), 256, 0, stream>>>(
        xz, conv_w, conv_b, xb);

    // 3. B_t / C_t and dtraw
    xproj_kernel<<<dim3(BT / 8), 256, 0, stream>>>(xb, x_proj_w, Btb, Ctb);
    dtraw_kernel<<<dim3(BT / 4), 256, 0, stream>>>(xb, x_proj_w, dtraw);

    // 4. chunked selective scan
    scan_kernel<<<dim3(BATCH * (DINNER / 16)), 256, 0, stream>>>(
        xb, dtraw, Btb, Ctb, A_log, dt_proj_w, dt_proj_b, yb);

    // 5. gate fuse -> bf16
    fuse_kernel<<<dim3((BT * DINNER) / (4 * 256)), 256, 0, stream>>>(
        yb, xb, xz, D_param, ygb);

    // 6. out = y @ c_proj_w (bf16 MFMA)
    gemm_bt<64, 128><<<dim3(DMODEL / 128, BT / 64), 256, 0, stream>>>(
        ygb, w2T, out, BT, DMODEL, DINNER);
}

// Round 3
// 196.913 us; speedup vs baseline: 4.2407x; 1.5239x over previous
//
#include <hip/hip_runtime.h>
#include <math.h>

#define DMODEL 1024
#define DSTATE 16
#define DCONV 4
#define DINNER 2048
#define BATCH 2
#define SEQ 1024
#define BT (BATCH*SEQ)   // 2048

typedef unsigned short ushort_t;
typedef __attribute__((ext_vector_type(8))) short short8;
typedef __attribute__((ext_vector_type(4))) float f32x4;

__device__ __forceinline__ ushort_t f2bf(float f) {
    union { float f; unsigned int u; } v; v.f = f;
    unsigned int r = v.u + 0x7fffu + ((v.u >> 16) & 1u);
    return (ushort_t)(r >> 16);
}

__device__ __forceinline__ float softplusf(float x) {
    return (x > 20.f) ? x : log1pf(__expf(x));
}

#define GLOAD_LDS16(G, L) \
  __builtin_amdgcn_global_load_lds((const __attribute__((address_space(1))) void*)(G), \
                                   (__attribute__((address_space(3))) void*)(L), 16, 0, 0)

// ---------------------------------------------------------------------------
__global__ __launch_bounds__(256) void zero_kernel(float* __restrict__ p)
{
    size_t i = ((size_t)blockIdx.x * 256 + threadIdx.x) * 4;
    *(float4*)&p[i] = make_float4(0.f, 0.f, 0.f, 0.f);
}

// ---------------------------------------------------------------------------
// cast fp32 -> bf16, same layout. 8 elems / thread.
// ---------------------------------------------------------------------------
__global__ __launch_bounds__(256) void cast_bf16_kernel(const float* __restrict__ in,
                                                        ushort_t* __restrict__ out)
{
    size_t i = ((size_t)blockIdx.x * 256 + threadIdx.x) * 8;
    float4 a = *(const float4*)&in[i];
    float4 b = *(const float4*)&in[i + 4];
    uint4 p;
    p.x = (unsigned)f2bf(a.x) | ((unsigned)f2bf(a.y) << 16);
    p.y = (unsigned)f2bf(a.z) | ((unsigned)f2bf(a.w) << 16);
    p.z = (unsigned)f2bf(b.x) | ((unsigned)f2bf(b.y) << 16);
    p.w = (unsigned)f2bf(b.z) | ((unsigned)f2bf(b.w) << 16);
    *(uint4*)&out[i] = p;
}

// ---------------------------------------------------------------------------
// transpose + cast: in [R][Cc] fp32 -> out [Cc][R] bf16.  grid (Cc/32, R/32).
// ---------------------------------------------------------------------------
__global__ __launch_bounds__(256) void transpose_cast_kernel(const float* __restrict__ in,
                                                             ushort_t* __restrict__ out,
                                                             int R, int Cc)
{
    __shared__ float t[32][33];
    const int r0 = blockIdx.y * 32;
    const int c0 = blockIdx.x * 32;
    const int tid = threadIdx.x;
    {
        int lr = tid >> 3, lc4 = (tid & 7) * 4;
        float4 v = *(const float4*)&in[(size_t)(r0 + lr) * Cc + c0 + lc4];
        t[lr][lc4 + 0] = v.x; t[lr][lc4 + 1] = v.y;
        t[lr][lc4 + 2] = v.z; t[lr][lc4 + 3] = v.w;
    }
    __syncthreads();
    {
        int oc = tid >> 3, rq = (tid & 7) * 4;
        ushort4 u;
        u.x = f2bf(t[rq + 0][oc]);
        u.y = f2bf(t[rq + 1][oc]);
        u.z = f2bf(t[rq + 2][oc]);
        u.w = f2bf(t[rq + 3][oc]);
        *(ushort4*)&out[(size_t)(c0 + oc) * R + r0 + rq] = u;
    }
}

// ---------------------------------------------------------------------------
// bf16 MFMA GEMM: C[M][N] (fp32) = A[M][K] @ Bt[N][K]^T, both bf16 row-major-K.
// ---------------------------------------------------------------------------
template<int BM, int BN>
__global__ __launch_bounds__(256) void gemm_bt(const ushort_t* __restrict__ A,
                                               const ushort_t* __restrict__ Bt,
                                               float* __restrict__ C,
                                               int M, int N, int K)
{
    constexpr int BK = 32;
    constexpr int AL = BM * BK / (256 * 8);
    constexpr int BL = BN * BK / (256 * 8);
    constexpr int FM = BM / 32;
    constexpr int FN = BN / 32;
    __shared__ __align__(16) ushort_t Al[BM * BK];
    __shared__ __align__(16) ushort_t Bl[BN * BK];

    const int tid  = threadIdx.x;
    const int lane = tid & 63;
    const int wid  = tid >> 6;
    const int wr   = wid >> 1;
    const int wc   = wid & 1;
    const int bm   = blockIdx.y * BM;
    const int bn   = blockIdx.x * BN;

    f32x4 acc[FM][FN] = {};

    for (int k0 = 0; k0 < K; k0 += BK) {
#pragma unroll
        for (int j = 0; j < AL; j++) {
            int chunk = j * 256 + tid;
            GLOAD_LDS16(&A[(size_t)(bm + (chunk >> 2)) * K + k0 + (chunk & 3) * 8],
                        &Al[(size_t)(j * 256 + wid * 64) * 8]);
        }
#pragma unroll
        for (int j = 0; j < BL; j++) {
            int chunk = j * 256 + tid;
            GLOAD_LDS16(&Bt[(size_t)(bn + (chunk >> 2)) * K + k0 + (chunk & 3) * 8],
                        &Bl[(size_t)(j * 256 + wid * 64) * 8]);
        }
        __syncthreads();

        short8 af[FM], bf[FN];
#pragma unroll
        for (int m = 0; m < FM; m++)
            af[m] = *(const short8*)&Al[(wr * (BM / 2) + m * 16 + (lane & 15)) * BK + (lane >> 4) * 8];
#pragma unroll
        for (int n = 0; n < FN; n++)
            bf[n] = *(const short8*)&Bl[(wc * (BN / 2) + n * 16 + (lane & 15)) * BK + (lane >> 4) * 8];
#pragma unroll
        for (int m = 0; m < FM; m++)
#pragma unroll
            for (int n = 0; n < FN; n++)
                acc[m][n] = __builtin_amdgcn_mfma_f32_16x16x32_bf16(af[m], bf[n], acc[m][n], 0, 0, 0);
        __syncthreads();
    }

#pragma unroll
    for (int m = 0; m < FM; m++)
#pragma unroll
        for (int n = 0; n < FN; n++) {
            int row0 = bm + wr * (BM / 2) + m * 16 + (lane >> 4) * 4;
            int col  = bn + wc * (BN / 2) + n * 16 + (lane & 15);
#pragma unroll
            for (int r = 0; r < 4; r++)
                C[(size_t)(row0 + r) * N + col] = acc[m][n][r];
        }
}

// ---------------------------------------------------------------------------
// Depthwise causal conv(4) + bias + SiLU, row-major out.
// ---------------------------------------------------------------------------
__global__ __launch_bounds__(256) void conv_silu_kernel(const float* __restrict__ xz,
                                                        const float* __restrict__ cw,
                                                        const float* __restrict__ cb,
                                                        float* __restrict__ xb_rm)
{
    __shared__ float tile[64 + 3][64];
    const int b  = blockIdx.z;
    const int t0 = blockIdx.x * 64;
    const int d0 = blockIdx.y * 64;
    const int tid = threadIdx.x;

    for (int e = tid; e < 67 * 16; e += 256) {
        int r  = e / 16;
        int c4 = (e % 16) * 4;
        int t  = t0 - 3 + r;
        float4 v = make_float4(0.f, 0.f, 0.f, 0.f);
        if (t >= 0)
            v = *(const float4*)&xz[((size_t)b * SEQ + t) * (2 * DINNER) + d0 + c4];
        *(float4*)&tile[r][c4] = v;
    }
    __syncthreads();

    const int dl = tid & 63;
    const int tb = tid >> 6;
    const int d  = d0 + dl;
    const float w0 = cw[d * 4 + 0], w1 = cw[d * 4 + 1];
    const float w2 = cw[d * 4 + 2], w3 = cw[d * 4 + 3];
    const float bias = cb[d];

#pragma unroll
    for (int ii = 0; ii < 16; ii++) {
        int tl = tb + 4 * ii;
        float s = bias;
        s = fmaf(tile[tl + 0][dl], w0, s);
        s = fmaf(tile[tl + 1][dl], w1, s);
        s = fmaf(tile[tl + 2][dl], w2, s);
        s = fmaf(tile[tl + 3][dl], w3, s);
        float sil = s / (1.f + __expf(-s));
        xb_rm[((size_t)b * SEQ + t0 + tl) * DINNER + d] = sil;
    }
}

// ---------------------------------------------------------------------------
// xproj v2: split-K. grid (BT/8, 8). Block: 8 rows x K-chunk 256.
// Stages xs[8][256] + ws[256][33] in LDS; inner loop pure LDS.
// Thread (r=tid>>5, n=tid&31): acc over 256 k for col n; dt partial folded in.
// atomicAdd into zero-initialized Btb/Ctb/dtraw (contiguous).
// ---------------------------------------------------------------------------
__global__ __launch_bounds__(256) void xproj_kernel(const float* __restrict__ xb,
                                                    const float* __restrict__ w,
                                                    float* __restrict__ Btb,
                                                    float* __restrict__ Ctb,
                                                    float* __restrict__ dtraw)
{
    __shared__ float xs[8][256];
    __shared__ float ws[256][33];
    const int bt0 = blockIdx.x * 8;
    const int kc  = blockIdx.y * 256;
    const int tid = threadIdx.x;
    const int r = tid >> 5, n = tid & 31;

    // stage xs (2048 floats, float4)
#pragma unroll
    for (int j = 0; j < 2; j++) {
        int e4 = (j * 256 + tid) * 4;
        int rr = e4 >> 8, cc = e4 & 255;
        *(float4*)&xs[rr][cc] = *(const float4*)&xb[(size_t)(bt0 + rr) * DINNER + kc + cc];
    }
    // stage ws (256*33 = 8448 floats, float4, linear copy)
    {
        const float* wsrc = w + (size_t)kc * 33;
        float* wdst = &ws[0][0];
        for (int e4 = tid; e4 < 2112; e4 += 256)
            *(float4*)&wdst[e4 * 4] = *(const float4*)&wsrc[e4 * 4];
    }
    __syncthreads();

    float acc = 0.f;
#pragma unroll 16
    for (int kk = 0; kk < 256; kk += 4) {
        float4 xv = *(const float4*)&xs[r][kk];
        acc = fmaf(xv.x, ws[kk + 0][n], acc);
        acc = fmaf(xv.y, ws[kk + 1][n], acc);
        acc = fmaf(xv.z, ws[kk + 2][n], acc);
        acc = fmaf(xv.w, ws[kk + 3][n], acc);
    }
    // dt column partial: this thread covers kk in [n*8, n*8+8)
    float dacc = 0.f;
#pragma unroll
    for (int j = 0; j < 8; j++)
        dacc = fmaf(xs[r][n * 8 + j], ws[n * 8 + j][32], dacc);
#pragma unroll
    for (int off = 16; off; off >>= 1)
        dacc += __shfl_xor(dacc, off, 32);

    if (n < 16) atomicAdd(&Btb[(bt0 + r) * 16 + n], acc);
    else        atomicAdd(&Ctb[(bt0 + r) * 16 + (n - 16)], acc);
    if (n == 0) atomicAdd(&dtraw[bt0 + r], dacc);
}

// ---------------------------------------------------------------------------
// Chunked selective scan v2: 4 d-channels x 64 chunks of 16 steps per block.
// grid: B * DINNER/4 = 1024 blocks, 256 threads (dl=tid&3, c=tid>>2).
// ---------------------------------------------------------------------------
__global__ __launch_bounds__(256) void scan_kernel(const float* __restrict__ xb,
                                                   const float* __restrict__ dtraw,
                                                   const float* __restrict__ Btb,
                                                   const float* __restrict__ Ctb,
                                                   const float* __restrict__ A_log,
                                                   const float* __restrict__ dtw,
                                                   const float* __restrict__ dtb,
                                                   float* __restrict__ y)
{
    __shared__ float Pl[64][4][16];
    __shared__ float Hl[64][4][16];
    const int tid = threadIdx.x;
    const int dl  = tid & 3;
    const int c   = tid >> 2;        // chunk 0..63
    const int b   = blockIdx.x >> 9;
    const int d   = ((blockIdx.x & 511) << 2) + dl;

    const float wdt = dtw[d];
    const float bdt = dtb[d];
    float As2[16];
#pragma unroll
    for (int s = 0; s < 16; s++)
        As2[s] = -__expf(A_log[d * 16 + s]) * 1.44269504f;

    const float* __restrict__ dtp = dtraw + b * SEQ;
    const float* __restrict__ xp  = xb + (size_t)b * SEQ * DINNER + d;
    const float* __restrict__ Bp  = Btb + (size_t)b * SEQ * 16;
    const float* __restrict__ Cp  = Ctb + (size_t)b * SEQ * 16;
    const int t0 = c * 16;

    float h[16], P[16];
#pragma unroll
    for (int s = 0; s < 16; s++) { h[s] = 0.f; P[s] = 1.f; }

#pragma unroll 2
    for (int i = 0; i < 16; i++) {
        const int t = t0 + i;
        float dt = softplusf(fmaf(dtp[t], wdt, bdt));
        float xv = xp[(size_t)t * DINNER];
        float Bv[16];
        *(float4*)&Bv[0]  = *(const float4*)&Bp[t * 16 + 0];
        *(float4*)&Bv[4]  = *(const float4*)&Bp[t * 16 + 4];
        *(float4*)&Bv[8]  = *(const float4*)&Bp[t * 16 + 8];
        *(float4*)&Bv[12] = *(const float4*)&Bp[t * 16 + 12];
        float dtx = dt * xv;
#pragma unroll
        for (int s = 0; s < 16; s++) {
            float a = exp2f(dt * As2[s]);
            P[s] *= a;
            h[s] = fmaf(a, h[s], Bv[s] * dtx);
        }
    }
#pragma unroll
    for (int s4 = 0; s4 < 4; s4++) {
        *(float4*)&Pl[c][dl][s4 * 4] = *(float4*)&P[s4 * 4];
        *(float4*)&Hl[c][dl][s4 * 4] = *(float4*)&h[s4 * 4];
    }
    __syncthreads();
    if (tid < 64) {   // carry propagate: thread (dl2, s2) walks 64 chunks
        const int dl2 = tid >> 4, s2 = tid & 15;
        float hs = 0.f;
        for (int cc = 0; cc < 64; cc++) {
            float Pv = Pl[cc][dl2][s2];
            float hv = Hl[cc][dl2][s2];
            Hl[cc][dl2][s2] = hs;
            hs = fmaf(Pv, hs, hv);
        }
    }
    __syncthreads();
#pragma unroll
    for (int s4 = 0; s4 < 4; s4++)
        *(float4*)&h[s4 * 4] = *(float4*)&Hl[c][dl][s4 * 4];

    float* __restrict__ yp = y + (size_t)b * SEQ * DINNER + d;
#pragma unroll 2
    for (int i = 0; i < 16; i++) {
        const int t = t0 + i;
        float dt = softplusf(fmaf(dtp[t], wdt, bdt));
        float xv = xp[(size_t)t * DINNER];
        float Bv[16], Cv[16];
        *(float4*)&Bv[0]  = *(const float4*)&Bp[t * 16 + 0];
        *(float4*)&Bv[4]  = *(const float4*)&Bp[t * 16 + 4];
        *(float4*)&Bv[8]  = *(const float4*)&Bp[t * 16 + 8];
        *(float4*)&Bv[12] = *(const float4*)&Bp[t * 16 + 12];
        *(float4*)&Cv[0]  = *(const float4*)&Cp[t * 16 + 0];
        *(float4*)&Cv[4]  = *(const float4*)&Cp[t * 16 + 4];
        *(float4*)&Cv[8]  = *(const float4*)&Cp[t * 16 + 8];
        *(float4*)&Cv[12] = *(const float4*)&Cp[t * 16 + 12];
        float dtx = dt * xv;
        float acc = 0.f;
#pragma unroll
        for (int s = 0; s < 16; s++) {
            float a = exp2f(dt * As2[s]);
            h[s] = fmaf(a, h[s], Bv[s] * dtx);
            acc = fmaf(h[s], Cv[s], acc);
        }
        yp[(size_t)t * DINNER] = acc;
    }
}

// ---------------------------------------------------------------------------
// y_final = (y_ssm + D*xb) * silu(z) -> bf16 for the out-proj GEMM.
// ---------------------------------------------------------------------------
__global__ __launch_bounds__(256) void fuse_kernel(const float* __restrict__ y,
                                                   const float* __restrict__ xb,
                                                   const float* __restrict__ xz,
                                                   const float* __restrict__ Dp,
                                                   ushort_t* __restrict__ out)
{
    size_t e  = ((size_t)blockIdx.x * 256 + threadIdx.x) * 4;
    size_t bt = e >> 11;
    int    d  = (int)(e & 2047);
    float4 yv = *(const float4*)&y[e];
    float4 xv = *(const float4*)&xb[e];
    float4 zv = *(const float4*)&xz[bt * (2 * DINNER) + DINNER + d];
    float4 dv = *(const float4*)&Dp[d];
    ushort4 u;
    u.x = f2bf(fmaf(dv.x, xv.x, yv.x) * (zv.x / (1.f + __expf(-zv.x))));
    u.y = f2bf(fmaf(dv.y, xv.y, yv.y) * (zv.y / (1.f + __expf(-zv.y))));
    u.z = f2bf(fmaf(dv.z, xv.z, yv.z) * (zv.z / (1.f + __expf(-zv.z))));
    u.w = f2bf(fmaf(dv.w, xv.w, yv.w) * (zv.w / (1.f + __expf(-zv.w))));
    *(ushort4*)&out[e] = u;
}

// ---------------------------------------------------------------------------
extern "C" void kernel_launch(void* const* d_in, const int* in_sizes, int n_in,
                              void* d_out, int out_size, void* d_ws, size_t ws_size,
                              hipStream_t stream)
{
    const float* x         = (const float*)d_in[0];
    const float* in_proj_w = (const float*)d_in[1];
    const float* conv_w    = (const float*)d_in[2];
    const float* conv_b    = (const float*)d_in[3];
    const float* x_proj_w  = (const float*)d_in[4];
    const float* dt_proj_w = (const float*)d_in[5];
    const float* dt_proj_b = (const float*)d_in[6];
    const float* A_log     = (const float*)d_in[7];
    const float* D_param   = (const float*)d_in[8];
    const float* c_proj_w  = (const float*)d_in[9];
    float* out = (float*)d_out;

    float* ws    = (float*)d_ws;
    float* xz    = ws;                                   // BT*4096 f32
    float* xb    = xz  + (size_t)BT * 4096;              // BT*2048 f32
    float* yb    = xb  + (size_t)BT * DINNER;            // BT*2048 f32
    float* Btb   = yb  + (size_t)BT * DINNER;            // BT*16
    float* Ctb   = Btb + (size_t)BT * 16;                // BT*16
    float* dtraw = Ctb + (size_t)BT * 16;                // BT   (B,C,dt contiguous = BT*33)
    ushort_t* xbf = (ushort_t*)(dtraw + BT);             // BT*1024 bf16
    ushort_t* w1T = xbf + (size_t)BT * DMODEL;           // 4096*1024 bf16
    ushort_t* w2T = w1T + (size_t)(2 * DINNER) * DMODEL; // 1024*2048 bf16
    ushort_t* ygb = w2T + (size_t)DMODEL * DINNER;       // BT*2048 bf16

    // zero B/C/dtraw accumulators (BT*33 = 67584 floats = 66 blocks * 1024)
    zero_kernel<<<dim3(66), 256, 0, stream>>>(Btb);

    // casts
    cast_bf16_kernel<<<dim3((BT * DMODEL) / (8 * 256)), 256, 0, stream>>>(x, xbf);
    transpose_cast_kernel<<<dim3((2 * DINNER) / 32, DMODEL / 32), 256, 0, stream>>>(
        in_proj_w, w1T, DMODEL, 2 * DINNER);
    transpose_cast_kernel<<<dim3(DMODEL / 32, DINNER / 32), 256, 0, stream>>>(
        c_proj_w, w2T, DINNER, DMODEL);

    // 1. xz = x @ in_proj_w (bf16 MFMA)
    gemm_bt<128, 128><<<dim3((2 * DINNER) / 128, BT / 128), 256, 0, stream>>>(
        xbf, w1T, xz, BT, 2 * DINNER, DMODEL);

    // 2. conv + bias + silu
    conv_silu_kernel<<<dim3(SEQ / 64, DINNER / 64, BATCH), 256, 0, stream>>>(
        xz, conv_w, conv_b, xb);

    // 3. x_ssm projection, split-K with atomics (includes dt column)
    xproj_kernel<<<dim3(BT / 8, 8), 256, 0, stream>>>(xb, x_proj_w, Btb, Ctb, dtraw);

    // 4. chunked selective scan (4 d / block)
    scan_kernel<<<dim3(BATCH * (DINNER / 4)), 256, 0, stream>>>(
        xb, dtraw, Btb, Ctb, A_log, dt_proj_w, dt_proj_b, yb);

    // 5. gate fuse -> bf16
    fuse_kernel<<<dim3((BT * DINNER) / (4 * 256)), 256, 0, stream>>>(
        yb, xb, xz, D_param, ygb);

    // 6. out = y @ c_proj_w (bf16 MFMA)
    gemm_bt<64, 128><<<dim3(DMODEL / 128, BT / 64), 256, 0, stream>>>(
        ygb, w2T, out, BT, DMODEL, DINNER);
}